// Round 1
// baseline (533.816 us; speedup 1.0000x reference)
//
#include <hip/hip_runtime.h>

// out[token, e] = W[e, idx[token]] + b[e]
// W: [128, V] row-major (fp32). Strategy: transpose W -> Wt [V, 128] in d_ws
// (coalesced gather afterwards), then float4 gather + bias add.

#define EMB 128

// ---- Kernel 1: tiled transpose W[128,V] -> Wt[V,128] ----------------------
// Block: 256 threads, tile = 64 vocab x 128 embed. LDS padded +1 (129) so both
// the strided LDS store and the contiguous LDS read are bank-conflict-free.
__global__ void transpose_W_kernel(const float* __restrict__ W,
                                   float* __restrict__ Wt, int V) {
    __shared__ float lds[64 * 129];
    const int v0 = blockIdx.x * 64;
    const int t  = threadIdx.x;

    // Load phase: coalesced along vocab (inner dim of W).
    #pragma unroll 8
    for (int j = t; j < 128 * 64; j += 256) {
        const int e    = j >> 6;    // 0..127
        const int vloc = j & 63;    // 0..63
        const int v    = v0 + vloc;
        float val = 0.0f;
        if (v < V) val = W[(size_t)e * V + v];
        lds[vloc * 129 + e] = val;  // consecutive lanes -> stride 129 -> no conflict
    }
    __syncthreads();

    // Store phase: coalesced along embed (inner dim of Wt).
    #pragma unroll 8
    for (int j = t; j < 64 * 128; j += 256) {
        const int vloc = j >> 7;    // 0..63
        const int e    = j & 127;   // 0..127
        const int v    = v0 + vloc;
        if (v < V) Wt[(size_t)v * EMB + e] = lds[vloc * 129 + e];
    }
}

// ---- Kernel 2: coalesced float4 gather + bias -----------------------------
// 32 consecutive threads = 1 token; thread's quad q = tid&31 is loop-invariant
// because the grid stride is a multiple of 32, so bias float4 is loaded once.
__global__ void gather_rows_kernel(const int* __restrict__ idx,
                                   const float* __restrict__ Wt,
                                   const float* __restrict__ bias,
                                   float* __restrict__ out, int ntok) {
    const int q = threadIdx.x & 31;
    const float4 bq = ((const float4*)bias)[q];

    const long long total  = (long long)ntok * 32;          // float4 tasks
    const long long stride = (long long)gridDim.x * blockDim.x;
    for (long long i = (long long)blockIdx.x * blockDim.x + threadIdx.x;
         i < total; i += stride) {
        const int token = (int)(i >> 5);
        const int row   = idx[token];                        // broadcast within 32
        float4 v = ((const float4*)(Wt + (size_t)row * EMB))[q];
        v.x += bq.x; v.y += bq.y; v.z += bq.z; v.w += bq.w;
        ((float4*)(out + (size_t)token * EMB))[q] = v;
    }
}

// ---- Fallback: direct (uncoalesced) gather if ws too small ----------------
__global__ void gather_direct_kernel(const int* __restrict__ idx,
                                     const float* __restrict__ W,
                                     const float* __restrict__ bias,
                                     float* __restrict__ out, int ntok, int V) {
    const long long total  = (long long)ntok * EMB;
    const long long stride = (long long)gridDim.x * blockDim.x;
    for (long long i = (long long)blockIdx.x * blockDim.x + threadIdx.x;
         i < total; i += stride) {
        const int token = (int)(i >> 7);
        const int e     = (int)(i & (EMB - 1));
        out[i] = W[(size_t)e * V + idx[token]] + bias[e];
    }
}

extern "C" void kernel_launch(void* const* d_in, const int* in_sizes, int n_in,
                              void* d_out, int out_size, void* d_ws, size_t ws_size,
                              hipStream_t stream) {
    const int*   x = (const int*)d_in[0];
    const float* W = (const float*)d_in[1];
    const float* b = (const float*)d_in[2];
    float* out = (float*)d_out;

    const int ntok = in_sizes[0];           // 4096*200 = 819200
    const int V    = in_sizes[1] / EMB;     // 100000

    const size_t need = (size_t)V * EMB * sizeof(float);  // 51.2 MB
    if (ws_size >= need) {
        float* Wt = (float*)d_ws;
        const int tblocks = (V + 63) / 64;
        transpose_W_kernel<<<tblocks, 256, 0, stream>>>(W, Wt, V);
        gather_rows_kernel<<<2048, 256, 0, stream>>>(x, Wt, b, out, ntok);
    } else {
        gather_direct_kernel<<<2048, 256, 0, stream>>>(x, W, b, out, ntok, V);
    }
}

// Round 3
// 515.973 us; speedup vs baseline: 1.0346x; 1.0346x over previous
//
#include <hip/hip_runtime.h>

// out[token, e] = W[e, idx[token]] + b[e]
// W: [128, V] row-major (fp32).
// Pass 1: transpose W -> Wt [V, 128] in d_ws (makes the gather coalesced).
// Pass 2: block = 64 tokens; idx staged in LDS once, then 8 independent
//         float4 gathers per thread (MLP=8) + nontemporal streaming store.

#define EMB 128
#define TOK_PER_BLK 64

typedef float fx4 __attribute__((ext_vector_type(4)));  // clang-native: OK for nontemporal

// ---- Kernel 1: tiled transpose W[128,V] -> Wt[V,128] ----------------------
__global__ void transpose_W_kernel(const float* __restrict__ W,
                                   float* __restrict__ Wt, int V) {
    __shared__ float lds[64 * 129];
    const int v0 = blockIdx.x * 64;
    const int t  = threadIdx.x;

    #pragma unroll 8
    for (int j = t; j < 128 * 64; j += 256) {
        const int e    = j >> 6;
        const int vloc = j & 63;
        const int v    = v0 + vloc;
        float val = 0.0f;
        if (v < V) val = W[(size_t)e * V + v];
        lds[vloc * 129 + e] = val;
    }
    __syncthreads();

    #pragma unroll 8
    for (int j = t; j < 64 * 128; j += 256) {
        const int vloc = j >> 7;
        const int e    = j & 127;
        const int v    = v0 + vloc;
        if (v < V) Wt[(size_t)v * EMB + e] = lds[vloc * 129 + e];
    }
}

// ---- Kernel 2: high-MLP gather + bias -------------------------------------
// 256 threads / block, 64 tokens / block. Thread t: q = t&31 (float4 slot),
// g = t>>5 (token subgroup). 8 independent gathers per thread.
__global__ void gather_rows_kernel(const int* __restrict__ idx,
                                   const float* __restrict__ Wt,
                                   const float* __restrict__ bias,
                                   float* __restrict__ out, int ntok) {
    __shared__ int rows[TOK_PER_BLK];
    const int t    = threadIdx.x;
    const int tok0 = blockIdx.x * TOK_PER_BLK;

    if (t < TOK_PER_BLK) {
        const int tok = tok0 + t;
        rows[t] = (tok < ntok) ? idx[tok] : 0;
    }
    __syncthreads();

    const int q = t & 31;
    const int g = t >> 5;
    const fx4 bq = ((const fx4*)bias)[q];

    fx4 v[8];
    #pragma unroll
    for (int p = 0; p < 8; ++p) {
        const int row = rows[g + p * 8];
        v[p] = ((const fx4*)(Wt + (size_t)row * EMB))[q];   // 8 independent loads
    }

    #pragma unroll
    for (int p = 0; p < 8; ++p) {
        const int tok = tok0 + g + p * 8;
        if (tok < ntok) {
            fx4 r = v[p] + bq;
            // streaming store: keep 419 MB of output out of LLC so Wt stays hot
            __builtin_nontemporal_store(r, (fx4*)(out + (size_t)tok * EMB) + q);
        }
    }
}

// ---- Fallback: direct gather if ws too small ------------------------------
__global__ void gather_direct_kernel(const int* __restrict__ idx,
                                     const float* __restrict__ W,
                                     const float* __restrict__ bias,
                                     float* __restrict__ out, int ntok, int V) {
    const long long total  = (long long)ntok * EMB;
    const long long stride = (long long)gridDim.x * blockDim.x;
    for (long long i = (long long)blockIdx.x * blockDim.x + threadIdx.x;
         i < total; i += stride) {
        const int token = (int)(i >> 7);
        const int e     = (int)(i & (EMB - 1));
        out[i] = W[(size_t)e * V + idx[token]] + bias[e];
    }
}

extern "C" void kernel_launch(void* const* d_in, const int* in_sizes, int n_in,
                              void* d_out, int out_size, void* d_ws, size_t ws_size,
                              hipStream_t stream) {
    const int*   x = (const int*)d_in[0];
    const float* W = (const float*)d_in[1];
    const float* b = (const float*)d_in[2];
    float* out = (float*)d_out;

    const int ntok = in_sizes[0];           // 819200
    const int V    = in_sizes[1] / EMB;     // 100000

    const size_t need = (size_t)V * EMB * sizeof(float);  // 51.2 MB
    if (ws_size >= need) {
        float* Wt = (float*)d_ws;
        const int tblocks = (V + 63) / 64;
        transpose_W_kernel<<<tblocks, 256, 0, stream>>>(W, Wt, V);
        const int gblocks = (ntok + TOK_PER_BLK - 1) / TOK_PER_BLK;
        gather_rows_kernel<<<gblocks, 256, 0, stream>>>(x, Wt, b, out, ntok);
    } else {
        gather_direct_kernel<<<2048, 256, 0, stream>>>(x, W, b, out, ntok, V);
    }
}